// Round 2
// baseline (16492.899 us; speedup 1.0000x reference)
//
#include <hip/hip_runtime.h>

#define WN 32768
#define LN 16
#define DN 128
#define WLN (WN * LN)        // 524288
#define NNODES 50000
#define FHN 384

// ---------- helpers ----------
__device__ __forceinline__ unsigned fenc(float f) {
  unsigned u = __float_as_uint(f);
  return (u & 0x80000000u) ? ~u : (u | 0x80000000u);
}
__device__ __forceinline__ float fdec(unsigned u) {
  unsigned v = (u & 0x80000000u) ? (u & 0x7FFFFFFFu) : ~u;
  return __uint_as_float(v);
}
__device__ __forceinline__ float sigm(float x) { return 1.f / (1.f + expf(-x)); }

// ---------- RMSNorm: one wave per row of 128 ----------
__global__ __launch_bounds__(256) void rmsnorm_k(const float* __restrict__ X,
                                                 const float* __restrict__ w,
                                                 float* __restrict__ out) {
  long row = (long)blockIdx.x * 4 + (threadIdx.x >> 6);
  int lane = threadIdx.x & 63;
  const float* x = X + row * 128;
  float v0 = x[lane], v1 = x[lane + 64];
  float ss = v0 * v0 + v1 * v1;
#pragma unroll
  for (int off = 32; off > 0; off >>= 1) ss += __shfl_down(ss, off);
  ss = __shfl(ss, 0);
  float r = rsqrtf(ss * (1.f / 128.f) + 1e-5f);
  out[row * 128 + lane] = v0 * r * w[lane];
  out[row * 128 + lane + 64] = v1 * r * w[lane + 64];
}

// ---------- generic fp32 GEMM: C[M,N] = A[M,K] @ B[N,K]^T (+bias) ----------
enum { EPI_STORE = 0, EPI_RELU = 1, EPI_ADD = 2 };

template <int EPI>
__global__ __launch_bounds__(256) void gemm_k(const float* __restrict__ A, int lda,
                                              const float* __restrict__ B, int ldb,
                                              const float* __restrict__ bias,
                                              float* __restrict__ C, int ldc,
                                              int M, int N, int K) {
  __shared__ float As[16][68];
  __shared__ float Bs[16][68];
  const int tid = threadIdx.x;
  const int bm = blockIdx.x * 64;
  const int bn = blockIdx.y * 64;
  const int lm = tid >> 2;
  const int lk = (tid & 3) << 2;
  const int tm = (tid >> 4) << 2;
  const int tn = (tid & 15) << 2;
  float acc[4][4] = {};
  for (int k0 = 0; k0 < K; k0 += 16) {
    float4 av = make_float4(0.f, 0.f, 0.f, 0.f);
    if (bm + lm < M)
      av = *reinterpret_cast<const float4*>(A + (long)(bm + lm) * lda + k0 + lk);
    As[lk + 0][lm] = av.x; As[lk + 1][lm] = av.y; As[lk + 2][lm] = av.z; As[lk + 3][lm] = av.w;
    float4 bv = *reinterpret_cast<const float4*>(B + (long)(bn + lm) * ldb + k0 + lk);
    Bs[lk + 0][lm] = bv.x; Bs[lk + 1][lm] = bv.y; Bs[lk + 2][lm] = bv.z; Bs[lk + 3][lm] = bv.w;
    __syncthreads();
#pragma unroll
    for (int k = 0; k < 16; k++) {
      float a[4], b[4];
#pragma unroll
      for (int j = 0; j < 4; j++) { a[j] = As[k][tm + j]; b[j] = Bs[k][tn + j]; }
#pragma unroll
      for (int i = 0; i < 4; i++)
#pragma unroll
        for (int j = 0; j < 4; j++) acc[i][j] = fmaf(a[i], b[j], acc[i][j]);
    }
    __syncthreads();
  }
#pragma unroll
  for (int i = 0; i < 4; i++) {
    int gm = bm + tm + i;
    if (gm < M) {
      float* crow = C + (long)gm * ldc + bn;
#pragma unroll
      for (int j = 0; j < 4; j++) {
        float v = acc[i][j];
        if (EPI == EPI_ADD) {
          crow[tn + j] += v;
        } else {
          if (bias) v += bias[bn + tn + j];
          if (EPI == EPI_RELU) v = fmaxf(v, 0.f);
          crow[tn + j] = v;
        }
      }
    }
  }
}

// ---------- fused SwiGLU gate: U = silu(A@W1^T) * (A@W3^T), K=128 ----------
__global__ __launch_bounds__(256) void ffn_gate_k(const float* __restrict__ A,
                                                  const float* __restrict__ W1,
                                                  const float* __restrict__ W3,
                                                  float* __restrict__ U, int M) {
  __shared__ float As[16][68];
  __shared__ float B1s[16][68];
  __shared__ float B3s[16][68];
  const int tid = threadIdx.x;
  const int bm = blockIdx.x * 64;
  const int bn = blockIdx.y * 64;
  const int lm = tid >> 2;
  const int lk = (tid & 3) << 2;
  const int tm = (tid >> 4) << 2;
  const int tn = (tid & 15) << 2;
  float acc1[4][4] = {}, acc3[4][4] = {};
  for (int k0 = 0; k0 < 128; k0 += 16) {
    float4 av = *reinterpret_cast<const float4*>(A + (long)(bm + lm) * 128 + k0 + lk);
    As[lk + 0][lm] = av.x; As[lk + 1][lm] = av.y; As[lk + 2][lm] = av.z; As[lk + 3][lm] = av.w;
    float4 b1 = *reinterpret_cast<const float4*>(W1 + (long)(bn + lm) * 128 + k0 + lk);
    B1s[lk + 0][lm] = b1.x; B1s[lk + 1][lm] = b1.y; B1s[lk + 2][lm] = b1.z; B1s[lk + 3][lm] = b1.w;
    float4 b3 = *reinterpret_cast<const float4*>(W3 + (long)(bn + lm) * 128 + k0 + lk);
    B3s[lk + 0][lm] = b3.x; B3s[lk + 1][lm] = b3.y; B3s[lk + 2][lm] = b3.z; B3s[lk + 3][lm] = b3.w;
    __syncthreads();
#pragma unroll
    for (int k = 0; k < 16; k++) {
      float a[4], b1v[4], b3v[4];
#pragma unroll
      for (int j = 0; j < 4; j++) {
        a[j] = As[k][tm + j]; b1v[j] = B1s[k][tn + j]; b3v[j] = B3s[k][tn + j];
      }
#pragma unroll
      for (int i = 0; i < 4; i++)
#pragma unroll
        for (int j = 0; j < 4; j++) {
          acc1[i][j] = fmaf(a[i], b1v[j], acc1[i][j]);
          acc3[i][j] = fmaf(a[i], b3v[j], acc3[i][j]);
        }
    }
    __syncthreads();
  }
#pragma unroll
  for (int i = 0; i < 4; i++) {
    float* crow = U + (long)(bm + tm + i) * FHN + bn;
#pragma unroll
    for (int j = 0; j < 4; j++) {
      float c1 = acc1[i][j];
      crow[tn + j] = c1 * sigm(c1) * acc3[i][j];
    }
  }
}

// ---------- GRU pointwise, one direction; state updated in place ----------
__global__ __launch_bounds__(256) void gru_pw_k(const float* __restrict__ gx,
                                                const float* __restrict__ gh,
                                                float* __restrict__ st) {
  int idx = blockIdx.x * 256 + threadIdx.x;  // WN*128
  int w = idx >> 7, d = idx & 127;
  long base = (long)w * 384;
  float rr = sigm(gx[base + d] + gh[base + d]);
  float zz = sigm(gx[base + 128 + d] + gh[base + 128 + d]);
  float nn = tanhf(gx[base + 256 + d] + rr * gh[base + 256 + d]);
  st[idx] = (1.f - zz) * nn + zz * st[idx];
}

// ---------- logits: [WL,128] @ [8,128]^T + b ----------
__global__ __launch_bounds__(256) void logits_k(const float* __restrict__ X,
                                                const float* __restrict__ LW,
                                                const float* __restrict__ LB,
                                                float* __restrict__ out) {
  __shared__ float w[1024];
  __shared__ float b[8];
  int tid = threadIdx.x;
  for (int i = tid; i < 1024; i += 256) w[i] = LW[i];
  if (tid < 8) b[tid] = LB[tid];
  __syncthreads();
  long r = (long)blockIdx.x * 32 + (tid >> 3);
  int hh = tid & 7;
  const float* x = X + r * 128;
  const float* wr = w + hh * 128;
  float s = 0.f;
#pragma unroll 16
  for (int k = 0; k < 128; k++) s = fmaf(x[k], wr[k], s);
  out[r * 8 + hh] = s + b[hh];
}

__global__ __launch_bounds__(256) void segmax_k(const float* __restrict__ logits,
                                                const int* __restrict__ seg,
                                                unsigned* __restrict__ menc) {
  long idx = (long)blockIdx.x * 256 + threadIdx.x;  // WL*8
  long i = idx >> 3;
  int hh = idx & 7;
  int s = seg[i];
  atomicMax(&menc[(long)s * 8 + hh], fenc(logits[idx]));
}

// in-place: e_or_logits holds logits on entry, e on exit
__global__ __launch_bounds__(256) void expdenom_k(float* __restrict__ e_or_logits,
                                                  const int* __restrict__ seg,
                                                  const unsigned* __restrict__ menc,
                                                  float* __restrict__ denom) {
  long idx = (long)blockIdx.x * 256 + threadIdx.x;  // WL*8
  long i = idx >> 3;
  int hh = idx & 7;
  int s = seg[i];
  float m = fdec(menc[(long)s * 8 + hh]);
  float ev = expf(e_or_logits[idx] - m);
  e_or_logits[idx] = ev;
  atomicAdd(&denom[(long)s * 8 + hh], ev);
}

__global__ __launch_bounds__(256) void scatter_k(const float* __restrict__ v,
                                                 const float* __restrict__ e,
                                                 const float* __restrict__ denom,
                                                 const int* __restrict__ seg,
                                                 float* __restrict__ node_emb) {
  long idx = (long)blockIdx.x * 256 + threadIdx.x;  // WL*128
  long i = idx >> 7;
  int d = idx & 127;
  int hh = d >> 4;
  int s = seg[i];
  float a = e[i * 8 + hh] / (denom[(long)s * 8 + hh] + 1e-9f);
  atomicAdd(&node_emb[(long)s * 128 + d], a * v[idx]);
}

__global__ __launch_bounds__(256) void gatheradd_k(float* __restrict__ x,
                                                   const float* __restrict__ back,
                                                   const int* __restrict__ seg) {
  long idx = (long)blockIdx.x * 256 + threadIdx.x;  // WL*32
  long i = idx >> 5;
  int d4 = (int)(idx & 31) << 2;
  int s = seg[i];
  float4 xv = *reinterpret_cast<float4*>(x + i * 128 + d4);
  float4 bv = *reinterpret_cast<const float4*>(back + (long)s * 128 + d4);
  xv.x += bv.x; xv.y += bv.y; xv.z += bv.z; xv.w += bv.w;
  *reinterpret_cast<float4*>(x + i * 128 + d4) = xv;
}

// ---------- final head dot: out[n] = h2[n,:] . w3 + b3 ----------
__global__ __launch_bounds__(256) void head3_k(const float* __restrict__ H2,
                                               const float* __restrict__ W3,
                                               const float* __restrict__ B3,
                                               float* __restrict__ out, int M) {
  int row = blockIdx.x * 4 + (threadIdx.x >> 6);
  int lane = threadIdx.x & 63;
  if (row >= M) return;
  const float* x = H2 + (long)row * 128;
  float s = x[lane] * W3[lane] + x[lane + 64] * W3[lane + 64];
#pragma unroll
  for (int off = 32; off > 0; off >>= 1) s += __shfl_down(s, off);
  if (lane == 0) out[row] = s + B3[0];
}

// ---------- host ----------
extern "C" void kernel_launch(void* const* d_in, const int* in_sizes, int n_in,
                              void* d_out, int out_size, void* d_ws, size_t ws_size,
                              hipStream_t stream) {
  (void)in_sizes; (void)n_in; (void)out_size; (void)ws_size;
  const float* in_x       = (const float*)d_in[0];
  const int*   seg        = (const int*)d_in[1];
  const float* gru_norm_w = (const float*)d_in[3];
  const float* wi_f       = (const float*)d_in[4];
  const float* wh_f       = (const float*)d_in[5];
  const float* bi_f       = (const float*)d_in[6];
  const float* bh_f       = (const float*)d_in[7];
  const float* wi_b       = (const float*)d_in[8];
  const float* wh_b       = (const float*)d_in[9];
  const float* bi_b       = (const float*)d_in[10];
  const float* bh_b       = (const float*)d_in[11];
  const float* gru_out_w  = (const float*)d_in[12];
  const float* ffn_norm_w = (const float*)d_in[13];
  const float* ffn_w1     = (const float*)d_in[14];
  const float* ffn_w2     = (const float*)d_in[15];
  const float* ffn_w3     = (const float*)d_in[16];
  const float* logit_w    = (const float*)d_in[17];
  const float* logit_b    = (const float*)d_in[18];
  const float* to_node_w  = (const float*)d_in[19];
  const float* to_node_b  = (const float*)d_in[20];
  const float* from_node_w= (const float*)d_in[21];
  const float* from_node_b= (const float*)d_in[22];
  const float* head_w1    = (const float*)d_in[23];
  const float* head_b1    = (const float*)d_in[24];
  const float* head_w2    = (const float*)d_in[25];
  const float* head_b2    = (const float*)d_in[26];
  const float* head_w3    = (const float*)d_in[27];
  const float* head_b3    = (const float*)d_in[28];
  float* out = (float*)d_out;

  // ---- workspace carve-up (floats); total ~659 MiB ----
  float* ws = (float*)d_ws;
  size_t o = 0;
  auto alloc = [&](size_t n) { float* p = ws + o; o += (n + 63) & ~(size_t)63; return p; };
  float* xbuf    = alloc((size_t)WLN * 128);   // 256 MB: residual stream x
  float* hbuf    = alloc((size_t)WLN * 128);   // 256 MB: rmsnorm(x); reused as v in attention
  float* gxb     = alloc((size_t)WN * 384);    // 48 MB
  float* ghb     = alloc((size_t)WN * 384);    // 48 MB
  float* state_f = alloc((size_t)WN * 128);    // 16 MB
  float* state_b = alloc((size_t)WN * 128);    // 16 MB
  float* ebuf    = alloc((size_t)WLN * 8);     // 16 MB: logits then e, in place
  unsigned* menc = (unsigned*)alloc((size_t)NNODES * 8);
  float* denomb  = alloc((size_t)NNODES * 8);
  // aliases (regions dead at time of reuse):
  float* uchunk   = gxb;       // FFN u chunk: 65536*384 = 25.17M floats = gxb+ghb exactly
  float* node_emb = state_f;   // 6.4M floats <= 8.39M (state_f+state_b)
  float* backb    = gxb;       // 6.4M <= 12.58M
  float* h1b      = gxb;
  float* h2b      = ghb;

  auto gemm = [&](int epi, const float* A, int lda, const float* B, int ldb,
                  const float* bias, float* C, int ldc, int M, int N, int K) {
    dim3 g((M + 63) / 64, N / 64);
    if (epi == EPI_STORE)
      hipLaunchKernelGGL((gemm_k<EPI_STORE>), g, dim3(256), 0, stream, A, lda, B, ldb, bias, C, ldc, M, N, K);
    else if (epi == EPI_RELU)
      hipLaunchKernelGGL((gemm_k<EPI_RELU>), g, dim3(256), 0, stream, A, lda, B, ldb, bias, C, ldc, M, N, K);
    else
      hipLaunchKernelGGL((gemm_k<EPI_ADD>), g, dim3(256), 0, stream, A, lda, B, ldb, bias, C, ldc, M, N, K);
  };

  hipMemcpyAsync(xbuf, in_x, (size_t)WLN * 128 * 4, hipMemcpyDeviceToDevice, stream);

  for (int it = 0; it < 2; ++it) {
    // --- GRU block ---
    hipLaunchKernelGGL(rmsnorm_k, dim3(WLN / 4), dim3(256), 0, stream, xbuf, gru_norm_w, hbuf);
    hipMemsetAsync(state_f, 0, (size_t)WN * 128 * 4, stream);
    hipMemsetAsync(state_b, 0, (size_t)WN * 128 * 4, stream);
    for (int t = 0; t < LN; ++t) {
      // forward direction: l = t
      gemm(EPI_STORE, hbuf + t * DN, LN * DN, wi_f, 128, bi_f, gxb, 384, WN, 384, 128);
      gemm(EPI_STORE, state_f, 128, wh_f, 128, bh_f, ghb, 384, WN, 384, 128);
      hipLaunchKernelGGL(gru_pw_k, dim3(WN * 128 / 256), dim3(256), 0, stream, gxb, ghb, state_f);
      gemm(EPI_ADD, state_f, 128, gru_out_w, 256, nullptr, xbuf + t * DN, LN * DN, WN, 128, 128);
      // backward direction: l = LN-1-t
      gemm(EPI_STORE, hbuf + (LN - 1 - t) * DN, LN * DN, wi_b, 128, bi_b, gxb, 384, WN, 384, 128);
      gemm(EPI_STORE, state_b, 128, wh_b, 128, bh_b, ghb, 384, WN, 384, 128);
      hipLaunchKernelGGL(gru_pw_k, dim3(WN * 128 / 256), dim3(256), 0, stream, gxb, ghb, state_b);
      gemm(EPI_ADD, state_b, 128, gru_out_w + 128, 256, nullptr, xbuf + (LN - 1 - t) * DN, LN * DN, WN, 128, 128);
    }

    // --- FFN (chunked: 8 chunks of 65536 rows; u chunk reuses gx/gh region) ---
    hipLaunchKernelGGL(rmsnorm_k, dim3(WLN / 4), dim3(256), 0, stream, xbuf, ffn_norm_w, hbuf);
    for (int c = 0; c < 8; ++c) {
      const int CM = WLN / 8;  // 65536
      dim3 g(CM / 64, FHN / 64);
      hipLaunchKernelGGL(ffn_gate_k, g, dim3(256), 0, stream,
                         hbuf + (size_t)c * CM * 128, ffn_w1, ffn_w3, uchunk, CM);
      gemm(EPI_ADD, uchunk, 384, ffn_w2, 384, nullptr, xbuf + (size_t)c * CM * 128, 128, CM, 128, 384);
    }

    // --- attention scatter ---
    hipLaunchKernelGGL(logits_k, dim3(WLN / 32), dim3(256), 0, stream, xbuf, logit_w, logit_b, ebuf);
    hipMemsetAsync(menc, 0, (size_t)NNODES * 8 * 4, stream);
    hipMemsetAsync(denomb, 0, (size_t)NNODES * 8 * 4, stream);
    hipMemsetAsync(node_emb, 0, (size_t)NNODES * 128 * 4, stream);
    hipLaunchKernelGGL(segmax_k, dim3(WLN * 8 / 256), dim3(256), 0, stream, ebuf, seg, menc);
    hipLaunchKernelGGL(expdenom_k, dim3(WLN * 8 / 256), dim3(256), 0, stream, ebuf, seg, menc, denomb);
    // v = x @ to_node_w^T + b  (into hbuf, which is free now)
    gemm(EPI_STORE, xbuf, 128, to_node_w, 128, to_node_b, hbuf, 128, WLN, 128, 128);
    hipLaunchKernelGGL(scatter_k, dim3((long)WLN * 128 / 256), dim3(256), 0, stream,
                       hbuf, ebuf, denomb, seg, node_emb);
    // back = node_emb @ from_node_w^T + b ; x += back[seg]
    gemm(EPI_STORE, node_emb, 128, from_node_w, 128, from_node_b, backb, 128, NNODES, 128, 128);
    hipLaunchKernelGGL(gatheradd_k, dim3(WLN * 32 / 256), dim3(256), 0, stream, xbuf, backb, seg);
  }

  // --- scoring head ---
  gemm(EPI_RELU, node_emb, 128, head_w1, 128, head_b1, h1b, 128, NNODES, 128, 128);
  gemm(EPI_RELU, h1b, 128, head_w2, 128, head_b2, h2b, 128, NNODES, 128, 128);
  hipLaunchKernelGGL(head3_k, dim3((NNODES + 3) / 4), dim3(256), 0, stream, h2b, head_w3, head_b3, out, NNODES);
}

// Round 3
// 8094.727 us; speedup vs baseline: 2.0375x; 2.0375x over previous
//
#include <hip/hip_runtime.h>
#include <hip/hip_bf16.h>

#define WN 32768
#define LN 16
#define DN 128
#define WLN (WN * LN)        // 524288
#define NNODES 50000
#define FHN 384

typedef __attribute__((ext_vector_type(8))) short short8;
typedef __attribute__((ext_vector_type(4))) float float4v;
typedef __hip_bfloat16 bf16;

__device__ __forceinline__ unsigned fenc(float f) {
  unsigned u = __float_as_uint(f);
  return (u & 0x80000000u) ? ~u : (u | 0x80000000u);
}
__device__ __forceinline__ float fdec(unsigned u) {
  unsigned v = (u & 0x80000000u) ? (u & 0x7FFFFFFFu) : ~u;
  return __uint_as_float(v);
}
__device__ __forceinline__ float sigm(float x) { return 1.f / (1.f + expf(-x)); }

// ---------- weight prep ----------
// Wcat2 [512][256]: rows 0..255 = (r,z): [wi | wh]; 256..383 = xn: [wi | 0]; 384..511 = hn: [0 | wh]
__global__ __launch_bounds__(256) void wcat2_k(const float* __restrict__ wi,
                                               const float* __restrict__ wh,
                                               bf16* __restrict__ W) {
  int idx = blockIdx.x * 256 + threadIdx.x;  // 512*256
  int n2 = idx >> 8, k2 = idx & 255;
  float v;
  if (n2 < 256)      v = (k2 < 128) ? wi[n2 * 128 + k2] : wh[n2 * 128 + (k2 - 128)];
  else if (n2 < 384) v = (k2 < 128) ? wi[n2 * 128 + k2] : 0.f;
  else               v = (k2 < 128) ? 0.f : wh[(n2 - 128) * 128 + (k2 - 128)];
  W[idx] = (bf16)v;
}

__global__ __launch_bounds__(256) void conv2d_k(const float* __restrict__ src, int ld,
                                                bf16* __restrict__ dst, int cols, int total) {
  int idx = blockIdx.x * 256 + threadIdx.x;
  if (idx >= total) return;
  int r = idx / cols, c = idx - r * cols;
  dst[idx] = (bf16)src[(size_t)r * ld + c];
}

// ---------- RMSNorm -> bf16 ----------
__global__ __launch_bounds__(256) void rmsnorm_bf16_k(const float* __restrict__ X,
                                                      const float* __restrict__ w,
                                                      bf16* __restrict__ out) {
  long row = (long)blockIdx.x * 4 + (threadIdx.x >> 6);
  int lane = threadIdx.x & 63;
  const float* x = X + row * 128;
  float v0 = x[lane], v1 = x[lane + 64];
  float ss = v0 * v0 + v1 * v1;
#pragma unroll
  for (int off = 32; off > 0; off >>= 1) ss += __shfl_down(ss, off);
  ss = __shfl(ss, 0);
  float r = rsqrtf(ss * (1.f / 128.f) + 1e-5f);
  out[row * 128 + lane] = (bf16)(v0 * r * w[lane]);
  out[row * 128 + lane + 64] = (bf16)(v1 * r * w[lane + 64]);
}

// ---------- fused GRU gate GEMM + pointwise ----------
// block: 256thr=4 waves, 64 rows/block, grid.x = WN/64
// A rows: k<128 -> hbase[row*2048 + k]; k>=128 -> state[row*128 + k-128]
__global__ __launch_bounds__(256, 2) void gru_gate_k(const bf16* __restrict__ hbase,
                                                     bf16* __restrict__ state,
                                                     const bf16* __restrict__ W,  // [512][256]
                                                     const float* __restrict__ bi,
                                                     const float* __restrict__ bh) {
  __shared__ __attribute__((aligned(16))) bf16 As[64][40];
  __shared__ __attribute__((aligned(16))) bf16 Bs[512][40];
  const int tid = threadIdx.x;
  const int wave = tid >> 6, lane = tid & 63;
  const long rb = (long)blockIdx.x * 64;
  float4v acc[32];
#pragma unroll
  for (int i = 0; i < 32; i++) acc[i] = (float4v)(0.f);

  for (int kc = 0; kc < 8; ++kc) {
    const int k0 = kc * 32;
    // stage A: 64x32, 512 quads, 2/thread
#pragma unroll
    for (int i = 0; i < 2; i++) {
      int q = tid + i * 256;
      int row = q >> 3, kq = (q & 7) * 4;
      const bf16* src = (k0 < 128) ? (hbase + (rb + row) * 2048 + k0 + kq)
                                   : (state + (rb + row) * 128 + (k0 - 128) + kq);
      *(ushort4*)&As[row][kq] = *(const ushort4*)src;
    }
    // stage B: 512x32, 4096 quads, 16/thread
#pragma unroll
    for (int i = 0; i < 16; i++) {
      int q = tid + i * 256;
      int row = q >> 3, kq = (q & 7) * 4;
      *(ushort4*)&Bs[row][kq] = *(const ushort4*)(W + (size_t)row * 256 + k0 + kq);
    }
    __syncthreads();
    short8 af = *(const short8*)&As[wave * 16 + (lane & 15)][(lane >> 4) * 8];
#pragma unroll
    for (int ct = 0; ct < 32; ++ct) {
      short8 bf = *(const short8*)&Bs[ct * 16 + (lane & 15)][(lane >> 4) * 8];
      acc[ct] = __builtin_amdgcn_mfma_f32_16x16x32_bf16(af, bf, acc[ct], 0, 0, 0);
    }
    __syncthreads();
  }
  // epilogue: acc[0..7]=r, [8..15]=z, [16..23]=xn, [24..31]=hn
  const int c = lane & 15, qd = lane >> 4;
#pragma unroll
  for (int ct = 0; ct < 8; ++ct) {
    int d = ct * 16 + c;
    float bR = bi[d] + bh[d];
    float bZ = bi[128 + d] + bh[128 + d];
    float bXN = bi[256 + d], bHN = bh[256 + d];
#pragma unroll
    for (int reg = 0; reg < 4; ++reg) {
      long w = rb + wave * 16 + qd * 4 + reg;
      float r = sigm(acc[ct][reg] + bR);
      float z = sigm(acc[ct + 8][reg] + bZ);
      float n = tanhf(acc[ct + 16][reg] + bXN + r * (acc[ct + 24][reg] + bHN));
      float hold = (float)state[w * 128 + d];
      state[w * 128 + d] = (bf16)((1.f - z) * n + z * hold);
    }
  }
}

// ---------- generic bf16 MFMA GEMM: C[M,128-panel] (+)= A@B^T ----------
template <int EPI>  // 0=store, 2=add
__global__ __launch_bounds__(256, 2) void mm_bf16_k(const bf16* __restrict__ A, int lda,
                                                    const bf16* __restrict__ B, int ldb,
                                                    float* __restrict__ C, int ldc, int K) {
  __shared__ __attribute__((aligned(16))) bf16 As[64][40];
  __shared__ __attribute__((aligned(16))) bf16 Bs[128][40];
  const int tid = threadIdx.x;
  const int wave = tid >> 6, lane = tid & 63;
  const long rb = (long)blockIdx.x * 64;
  const int nb = blockIdx.y * 128;
  float4v acc[8];
#pragma unroll
  for (int i = 0; i < 8; i++) acc[i] = (float4v)(0.f);
  for (int k0 = 0; k0 < K; k0 += 32) {
#pragma unroll
    for (int i = 0; i < 2; i++) {
      int q = tid + i * 256;
      int row = q >> 3, kq = (q & 7) * 4;
      *(ushort4*)&As[row][kq] = *(const ushort4*)(A + (rb + row) * (size_t)lda + k0 + kq);
    }
#pragma unroll
    for (int i = 0; i < 4; i++) {
      int q = tid + i * 256;
      int row = q >> 3, kq = (q & 7) * 4;
      *(ushort4*)&Bs[row][kq] = *(const ushort4*)(B + (size_t)(nb + row) * ldb + k0 + kq);
    }
    __syncthreads();
    short8 af = *(const short8*)&As[wave * 16 + (lane & 15)][(lane >> 4) * 8];
#pragma unroll
    for (int ct = 0; ct < 8; ++ct) {
      short8 bf = *(const short8*)&Bs[ct * 16 + (lane & 15)][(lane >> 4) * 8];
      acc[ct] = __builtin_amdgcn_mfma_f32_16x16x32_bf16(af, bf, acc[ct], 0, 0, 0);
    }
    __syncthreads();
  }
  const int c = lane & 15, qd = lane >> 4;
#pragma unroll
  for (int ct = 0; ct < 8; ++ct) {
    int n = nb + ct * 16 + c;
#pragma unroll
    for (int reg = 0; reg < 4; ++reg) {
      long row = rb + wave * 16 + qd * 4 + reg;
      if (EPI == 2) C[row * ldc + n] += acc[ct][reg];
      else C[row * ldc + n] = acc[ct][reg];
    }
  }
}

// ---------- fused SwiGLU gate (bf16 MFMA): U = silu(A@W1^T)*(A@W3^T) ----------
// W13 [768][128]: rows 0..383 = W1, 384..767 = W3. grid (M/64, 3)
__global__ __launch_bounds__(256, 2) void ffn_gate2_k(const bf16* __restrict__ A,
                                                      const bf16* __restrict__ W13,
                                                      bf16* __restrict__ U) {
  __shared__ __attribute__((aligned(16))) bf16 As[64][40];
  __shared__ __attribute__((aligned(16))) bf16 Bs[256][40];
  const int tid = threadIdx.x;
  const int wave = tid >> 6, lane = tid & 63;
  const long rb = (long)blockIdx.x * 64;
  const int nb = blockIdx.y * 128;
  float4v a1[8], a3[8];
#pragma unroll
  for (int i = 0; i < 8; i++) { a1[i] = (float4v)(0.f); a3[i] = (float4v)(0.f); }
  for (int k0 = 0; k0 < 128; k0 += 32) {
#pragma unroll
    for (int i = 0; i < 2; i++) {
      int q = tid + i * 256;
      int row = q >> 3, kq = (q & 7) * 4;
      *(ushort4*)&As[row][kq] = *(const ushort4*)(A + (rb + row) * 128 + k0 + kq);
    }
#pragma unroll
    for (int i = 0; i < 8; i++) {
      int q = tid + i * 256;
      int row = q >> 3, kq = (q & 7) * 4;
      int srcrow = (row < 128) ? (nb + row) : (384 + nb + row - 128);
      *(ushort4*)&Bs[row][kq] = *(const ushort4*)(W13 + (size_t)srcrow * 128 + k0 + kq);
    }
    __syncthreads();
    short8 af = *(const short8*)&As[wave * 16 + (lane & 15)][(lane >> 4) * 8];
#pragma unroll
    for (int ct = 0; ct < 8; ++ct) {
      short8 b1 = *(const short8*)&Bs[ct * 16 + (lane & 15)][(lane >> 4) * 8];
      a1[ct] = __builtin_amdgcn_mfma_f32_16x16x32_bf16(af, b1, a1[ct], 0, 0, 0);
      short8 b3 = *(const short8*)&Bs[128 + ct * 16 + (lane & 15)][(lane >> 4) * 8];
      a3[ct] = __builtin_amdgcn_mfma_f32_16x16x32_bf16(af, b3, a3[ct], 0, 0, 0);
    }
    __syncthreads();
  }
  const int c = lane & 15, qd = lane >> 4;
#pragma unroll
  for (int ct = 0; ct < 8; ++ct) {
    int d = nb + ct * 16 + c;
#pragma unroll
    for (int reg = 0; reg < 4; ++reg) {
      long row = rb + wave * 16 + qd * 4 + reg;
      float g = a1[ct][reg];
      U[row * 384 + d] = (bf16)(g * sigm(g) * a3[ct][reg]);
    }
  }
}

// ---------- fp32 GEMM (kept for precision-critical small paths) ----------
enum { EPI_STORE = 0, EPI_RELU = 1 };
template <int EPI>
__global__ __launch_bounds__(256) void gemm_k(const float* __restrict__ A, int lda,
                                              const float* __restrict__ B, int ldb,
                                              const float* __restrict__ bias,
                                              float* __restrict__ C, int ldc,
                                              int M, int N, int K) {
  __shared__ float As[16][68];
  __shared__ float Bs[16][68];
  const int tid = threadIdx.x;
  const int bm = blockIdx.x * 64;
  const int bn = blockIdx.y * 64;
  const int lm = tid >> 2;
  const int lk = (tid & 3) << 2;
  const int tm = (tid >> 4) << 2;
  const int tn = (tid & 15) << 2;
  float acc[4][4] = {};
  for (int k0 = 0; k0 < K; k0 += 16) {
    float4 av = make_float4(0.f, 0.f, 0.f, 0.f);
    if (bm + lm < M)
      av = *reinterpret_cast<const float4*>(A + (long)(bm + lm) * lda + k0 + lk);
    As[lk + 0][lm] = av.x; As[lk + 1][lm] = av.y; As[lk + 2][lm] = av.z; As[lk + 3][lm] = av.w;
    float4 bv = *reinterpret_cast<const float4*>(B + (long)(bn + lm) * ldb + k0 + lk);
    Bs[lk + 0][lm] = bv.x; Bs[lk + 1][lm] = bv.y; Bs[lk + 2][lm] = bv.z; Bs[lk + 3][lm] = bv.w;
    __syncthreads();
#pragma unroll
    for (int k = 0; k < 16; k++) {
      float a[4], b[4];
#pragma unroll
      for (int j = 0; j < 4; j++) { a[j] = As[k][tm + j]; b[j] = Bs[k][tn + j]; }
#pragma unroll
      for (int i = 0; i < 4; i++)
#pragma unroll
        for (int j = 0; j < 4; j++) acc[i][j] = fmaf(a[i], b[j], acc[i][j]);
    }
    __syncthreads();
  }
#pragma unroll
  for (int i = 0; i < 4; i++) {
    int gm = bm + tm + i;
    if (gm < M) {
      float* crow = C + (long)gm * ldc + bn;
#pragma unroll
      for (int j = 0; j < 4; j++) {
        float v = acc[i][j] + (bias ? bias[bn + tn + j] : 0.f);
        if (EPI == EPI_RELU) v = fmaxf(v, 0.f);
        crow[tn + j] = v;
      }
    }
  }
}

// ---------- to_node GEMM (fp32) fused with attention scatter ----------
__global__ __launch_bounds__(256) void tonode_scatter_k(const float* __restrict__ A,
                                                        const float* __restrict__ B,
                                                        const float* __restrict__ bias,
                                                        const float* __restrict__ e,
                                                        const float* __restrict__ denom,
                                                        const int* __restrict__ seg,
                                                        float* __restrict__ node_emb) {
  __shared__ float As[16][68];
  __shared__ float Bs[16][68];
  const int tid = threadIdx.x;
  const long bm = (long)blockIdx.x * 64;
  const int bn = blockIdx.y * 64;
  const int lm = tid >> 2;
  const int lk = (tid & 3) << 2;
  const int tm = (tid >> 4) << 2;
  const int tn = (tid & 15) << 2;
  float acc[4][4] = {};
  for (int k0 = 0; k0 < 128; k0 += 16) {
    float4 av = *reinterpret_cast<const float4*>(A + (bm + lm) * 128 + k0 + lk);
    As[lk + 0][lm] = av.x; As[lk + 1][lm] = av.y; As[lk + 2][lm] = av.z; As[lk + 3][lm] = av.w;
    float4 bv = *reinterpret_cast<const float4*>(B + (long)(bn + lm) * 128 + k0 + lk);
    Bs[lk + 0][lm] = bv.x; Bs[lk + 1][lm] = bv.y; Bs[lk + 2][lm] = bv.z; Bs[lk + 3][lm] = bv.w;
    __syncthreads();
#pragma unroll
    for (int k = 0; k < 16; k++) {
      float a[4], b[4];
#pragma unroll
      for (int j = 0; j < 4; j++) { a[j] = As[k][tm + j]; b[j] = Bs[k][tn + j]; }
#pragma unroll
      for (int i = 0; i < 4; i++)
#pragma unroll
        for (int j = 0; j < 4; j++) acc[i][j] = fmaf(a[i], b[j], acc[i][j]);
    }
    __syncthreads();
  }
#pragma unroll
  for (int i = 0; i < 4; i++) {
    long row = bm + tm + i;
    int s = seg[row];
#pragma unroll
    for (int j = 0; j < 4; j++) {
      int d = bn + tn + j;
      int hh = d >> 4;
      float a = e[row * 8 + hh] / (denom[(long)s * 8 + hh] + 1e-9f);
      atomicAdd(&node_emb[(long)s * 128 + d], a * (acc[i][j] + bias[d]));
    }
  }
}

// ---------- attention pointwise ----------
__global__ __launch_bounds__(256) void logits_k(const float* __restrict__ X,
                                                const float* __restrict__ LW,
                                                const float* __restrict__ LB,
                                                float* __restrict__ out) {
  __shared__ float w[1024];
  __shared__ float b[8];
  int tid = threadIdx.x;
  for (int i = tid; i < 1024; i += 256) w[i] = LW[i];
  if (tid < 8) b[tid] = LB[tid];
  __syncthreads();
  long r = (long)blockIdx.x * 32 + (tid >> 3);
  int hh = tid & 7;
  const float* x = X + r * 128;
  const float* wr = w + hh * 128;
  float s = 0.f;
#pragma unroll 16
  for (int k = 0; k < 128; k++) s = fmaf(x[k], wr[k], s);
  out[r * 8 + hh] = s + b[hh];
}

__global__ __launch_bounds__(256) void segmax_k(const float* __restrict__ logits,
                                                const int* __restrict__ seg,
                                                unsigned* __restrict__ menc) {
  long idx = (long)blockIdx.x * 256 + threadIdx.x;
  long i = idx >> 3;
  int hh = idx & 7;
  atomicMax(&menc[(long)seg[i] * 8 + hh], fenc(logits[idx]));
}

__global__ __launch_bounds__(256) void expdenom_k(float* __restrict__ e_or_logits,
                                                  const int* __restrict__ seg,
                                                  const unsigned* __restrict__ menc,
                                                  float* __restrict__ denom) {
  long idx = (long)blockIdx.x * 256 + threadIdx.x;
  long i = idx >> 3;
  int hh = idx & 7;
  int s = seg[i];
  float ev = expf(e_or_logits[idx] - fdec(menc[(long)s * 8 + hh]));
  e_or_logits[idx] = ev;
  atomicAdd(&denom[(long)s * 8 + hh], ev);
}

__global__ __launch_bounds__(256) void gatheradd_k(float* __restrict__ x,
                                                   const float* __restrict__ back,
                                                   const int* __restrict__ seg) {
  long idx = (long)blockIdx.x * 256 + threadIdx.x;
  long i = idx >> 5;
  int d4 = (int)(idx & 31) << 2;
  int s = seg[i];
  float4 xv = *reinterpret_cast<float4*>(x + i * 128 + d4);
  float4 bv = *reinterpret_cast<const float4*>(back + (long)s * 128 + d4);
  xv.x += bv.x; xv.y += bv.y; xv.z += bv.z; xv.w += bv.w;
  *reinterpret_cast<float4*>(x + i * 128 + d4) = xv;
}

__global__ __launch_bounds__(256) void head3_k(const float* __restrict__ H2,
                                               const float* __restrict__ W3,
                                               const float* __restrict__ B3,
                                               float* __restrict__ out, int M) {
  int row = blockIdx.x * 4 + (threadIdx.x >> 6);
  int lane = threadIdx.x & 63;
  if (row >= M) return;
  const float* x = H2 + (long)row * 128;
  float s = x[lane] * W3[lane] + x[lane + 64] * W3[lane + 64];
#pragma unroll
  for (int off = 32; off > 0; off >>= 1) s += __shfl_down(s, off);
  if (lane == 0) out[row] = s + B3[0];
}

// ---------- host ----------
extern "C" void kernel_launch(void* const* d_in, const int* in_sizes, int n_in,
                              void* d_out, int out_size, void* d_ws, size_t ws_size,
                              hipStream_t stream) {
  (void)in_sizes; (void)n_in; (void)out_size; (void)ws_size;
  const float* in_x       = (const float*)d_in[0];
  const int*   seg        = (const int*)d_in[1];
  const float* gru_norm_w = (const float*)d_in[3];
  const float* wi_f       = (const float*)d_in[4];
  const float* wh_f       = (const float*)d_in[5];
  const float* bi_f       = (const float*)d_in[6];
  const float* bh_f       = (const float*)d_in[7];
  const float* wi_b       = (const float*)d_in[8];
  const float* wh_b       = (const float*)d_in[9];
  const float* bi_b       = (const float*)d_in[10];
  const float* bh_b       = (const float*)d_in[11];
  const float* gru_out_w  = (const float*)d_in[12];
  const float* ffn_norm_w = (const float*)d_in[13];
  const float* ffn_w1     = (const float*)d_in[14];
  const float* ffn_w2     = (const float*)d_in[15];
  const float* ffn_w3     = (const float*)d_in[16];
  const float* logit_w    = (const float*)d_in[17];
  const float* logit_b    = (const float*)d_in[18];
  const float* to_node_w  = (const float*)d_in[19];
  const float* to_node_b  = (const float*)d_in[20];
  const float* from_node_w= (const float*)d_in[21];
  const float* from_node_b= (const float*)d_in[22];
  const float* head_w1    = (const float*)d_in[23];
  const float* head_b1    = (const float*)d_in[24];
  const float* head_w2    = (const float*)d_in[25];
  const float* head_b2    = (const float*)d_in[26];
  const float* head_w3    = (const float*)d_in[27];
  const float* head_b3    = (const float*)d_in[28];
  float* out = (float*)d_out;

  // ---- workspace carve-up (float slots), ~595 MB ----
  float* ws = (float*)d_ws;
  size_t o = 0;
  auto alloc = [&](size_t n) { float* p = ws + o; o += (n + 63) & ~(size_t)63; return p; };
  float* xbuf    = alloc((size_t)WLN * 128);          // 268 MB
  bf16*  hb16    = (bf16*)alloc((size_t)WLN * 64);    // 134 MB (WLN*128 bf16)
  bf16*  ub16    = (bf16*)alloc((size_t)WLN / 8 * 192);// 50 MB (65536*384 bf16)
  bf16*  state_f = (bf16*)alloc((size_t)WN * 64);     // 8.4 MB
  bf16*  state_b = (bf16*)alloc((size_t)WN * 64);
  float* ebuf    = alloc((size_t)WLN * 8);            // 16.8 MB
  unsigned* menc = (unsigned*)alloc((size_t)NNODES * 8);
  float* denomb  = alloc((size_t)NNODES * 8);
  float* node_emb= alloc((size_t)NNODES * 128);       // 25.6 MB
  float* backb   = alloc((size_t)NNODES * 128);
  float* h1b     = alloc((size_t)NNODES * 128);
  float* h2b     = alloc((size_t)NNODES * 128);
  bf16* Wcat2_f  = (bf16*)alloc(512 * 256 / 2);
  bf16* Wcat2_b  = (bf16*)alloc(512 * 256 / 2);
  bf16* WoF      = (bf16*)alloc(128 * 128 / 2);
  bf16* WoB      = (bf16*)alloc(128 * 128 / 2);
  bf16* W13      = (bf16*)alloc(768 * 128 / 2);
  bf16* W2b      = (bf16*)alloc(128 * 384 / 2);

  // ---- weight conversion ----
  hipLaunchKernelGGL(wcat2_k, dim3(512), dim3(256), 0, stream, wi_f, wh_f, Wcat2_f);
  hipLaunchKernelGGL(wcat2_k, dim3(512), dim3(256), 0, stream, wi_b, wh_b, Wcat2_b);
  hipLaunchKernelGGL(conv2d_k, dim3(64), dim3(256), 0, stream, gru_out_w, 256, WoF, 128, 128 * 128);
  hipLaunchKernelGGL(conv2d_k, dim3(64), dim3(256), 0, stream, gru_out_w + 128, 256, WoB, 128, 128 * 128);
  hipLaunchKernelGGL(conv2d_k, dim3(192), dim3(256), 0, stream, ffn_w1, 128, W13, 128, 384 * 128);
  hipLaunchKernelGGL(conv2d_k, dim3(192), dim3(256), 0, stream, ffn_w3, 128, W13 + 384 * 128, 128, 384 * 128);
  hipLaunchKernelGGL(conv2d_k, dim3(192), dim3(256), 0, stream, ffn_w2, 384, W2b, 384, 128 * 384);

  hipMemcpyAsync(xbuf, in_x, (size_t)WLN * 128 * 4, hipMemcpyDeviceToDevice, stream);

  for (int it = 0; it < 2; ++it) {
    // --- GRU block ---
    hipLaunchKernelGGL(rmsnorm_bf16_k, dim3(WLN / 4), dim3(256), 0, stream, xbuf, gru_norm_w, hb16);
    hipMemsetAsync(state_f, 0, (size_t)WN * 128 * 2, stream);
    hipMemsetAsync(state_b, 0, (size_t)WN * 128 * 2, stream);
    for (int t = 0; t < LN; ++t) {
      // forward: l = t
      hipLaunchKernelGGL(gru_gate_k, dim3(WN / 64), dim3(256), 0, stream,
                         hb16 + (size_t)t * 128, state_f, Wcat2_f, bi_f, bh_f);
      hipLaunchKernelGGL((mm_bf16_k<2>), dim3(WN / 64, 1), dim3(256), 0, stream,
                         state_f, 128, WoF, 128, xbuf + (size_t)t * 128, 2048, 128);
      // backward: l = 15 - t
      hipLaunchKernelGGL(gru_gate_k, dim3(WN / 64), dim3(256), 0, stream,
                         hb16 + (size_t)(LN - 1 - t) * 128, state_b, Wcat2_b, bi_b, bh_b);
      hipLaunchKernelGGL((mm_bf16_k<2>), dim3(WN / 64, 1), dim3(256), 0, stream,
                         state_b, 128, WoB, 128, xbuf + (size_t)(LN - 1 - t) * 128, 2048, 128);
    }

    // --- FFN (8 chunks of 65536 rows) ---
    hipLaunchKernelGGL(rmsnorm_bf16_k, dim3(WLN / 4), dim3(256), 0, stream, xbuf, ffn_norm_w, hb16);
    for (int c = 0; c < 8; ++c) {
      const int CM = WLN / 8;
      hipLaunchKernelGGL(ffn_gate2_k, dim3(CM / 64, 3), dim3(256), 0, stream,
                         hb16 + (size_t)c * CM * 128, W13, ub16);
      hipLaunchKernelGGL((mm_bf16_k<2>), dim3(CM / 64, 1), dim3(256), 0, stream,
                         ub16, 384, W2b, 384, xbuf + (size_t)c * CM * 128, 128, 384);
    }

    // --- attention scatter ---
    hipLaunchKernelGGL(logits_k, dim3(WLN / 32), dim3(256), 0, stream, xbuf, logit_w, logit_b, ebuf);
    hipMemsetAsync(menc, 0, (size_t)NNODES * 8 * 4, stream);
    hipMemsetAsync(denomb, 0, (size_t)NNODES * 8 * 4, stream);
    hipMemsetAsync(node_emb, 0, (size_t)NNODES * 128 * 4, stream);
    hipLaunchKernelGGL(segmax_k, dim3(WLN * 8 / 256), dim3(256), 0, stream, ebuf, seg, menc);
    hipLaunchKernelGGL(expdenom_k, dim3(WLN * 8 / 256), dim3(256), 0, stream, ebuf, seg, menc, denomb);
    hipLaunchKernelGGL(tonode_scatter_k, dim3(WLN / 64, 2), dim3(256), 0, stream,
                       xbuf, to_node_w, to_node_b, ebuf, denomb, seg, node_emb);
    hipLaunchKernelGGL((gemm_k<EPI_STORE>), dim3((NNODES + 63) / 64, 2), dim3(256), 0, stream,
                       node_emb, 128, from_node_w, 128, from_node_b, backb, 128, NNODES, 128, 128);
    hipLaunchKernelGGL(gatheradd_k, dim3(WLN * 32 / 256), dim3(256), 0, stream, xbuf, backb, seg);
  }

  // --- scoring head (fp32) ---
  hipLaunchKernelGGL((gemm_k<EPI_RELU>), dim3((NNODES + 63) / 64, 2), dim3(256), 0, stream,
                     node_emb, 128, head_w1, 128, head_b1, h1b, 128, NNODES, 128, 128);
  hipLaunchKernelGGL((gemm_k<EPI_RELU>), dim3((NNODES + 63) / 64, 2), dim3(256), 0, stream,
                     h1b, 128, head_w2, 128, head_b2, h2b, 128, NNODES, 128, 128);
  hipLaunchKernelGGL(head3_k, dim3((NNODES + 3) / 4), dim3(256), 0, stream, h2b, head_w3, head_b3, out, NNODES);
}